// Round 7
// baseline (221.255 us; speedup 1.0000x reference)
//
#include <hip/hip_runtime.h>

// ODE-RNN encoder: B=2048, T=64, HID=16, adaptive Tsit5 + GRU.
// Round 7: 32 lanes/sample (K-split x2), 2 samples/wave, 1024 blocks x 64
// -> 4 waves/CU = 1 wave on every SIMD (was 2 idle SIMDs/CU).
// Lane = 32s + 16q + j. y is plain-replicated per 16-lane row; lane (q,j)
// accumulates out[(j+8q)&15] over i in {j..j+7}; ds_swizzle xor 0x18 joins
// complementary halves; row_ror:8 + select normalizes q=1 back to plain.

#define T_STEPS 64
#define NB 2048
#define N_ODE_STEPS 16

// row_ror:r  => dst lane n gets src lane (n - r) & 15 (within 16-lane row)
#define ROR(x, r) __int_as_float(__builtin_amdgcn_update_dpp( \
    0, __float_as_int(x), 0x120 + (r), 0xF, 0xF, true))
// BitMode swizzle within 32 lanes: fetch lane id ^ 0x18 (flip q-bit and j-bit3)
#define SWZ18(x) __int_as_float(__builtin_amdgcn_ds_swizzle(__float_as_int(x), 0x601F))

__device__ __forceinline__ float rsum16(float v) {
  v += ROR(v, 8);
  v += ROR(v, 4);
  v += ROR(v, 2);
  v += ROR(v, 1);
  return v;  // all 16 lanes of each row hold the row sum
}

// G[c] = y[(j+c)&15] at every lane (rows are full plain copies of y)
__device__ __forceinline__ void gather8(float y, float (&G)[8]) {
  G[0] = y;
  G[1] = ROR(y, 15);
  G[2] = ROR(y, 14);
  G[3] = ROR(y, 13);
  G[4] = ROR(y, 12);
  G[5] = ROR(y, 11);
  G[6] = ROR(y, 10);
  G[7] = ROR(y, 9);
}

// w[c] = W[(j+8q)&15][(j+c)&15]. Returns bias + W.y (plain layout, all lanes).
__device__ __forceinline__ float dot8(const float (&w)[8], const float (&G)[8],
                                      bool isq1, float bias) {
  float a0 = w[0] * G[0];
  float a1 = w[1] * G[1];
  a0 = fmaf(w[2], G[2], a0);
  a1 = fmaf(w[3], G[3], a1);
  a0 = fmaf(w[4], G[4], a0);
  a1 = fmaf(w[5], G[5], a1);
  a0 = fmaf(w[6], G[6], a0);
  a1 = fmaf(w[7], G[7], a1);
  float acc = a0 + a1;                 // partial of out[(j+8q)&15]
  float red = acc + SWZ18(acc);        // + complementary half (same output row)
  float fix = ROR(red, 8);             // q=1 rows: out[j] sits at position j+8
  float r = isq1 ? fix : red;          // normalize to plain layout
  return r + bias;
}

__device__ __forceinline__ float fast_tanh(float x) {
  float e = __builtin_amdgcn_exp2f(x * 2.885390081777927f);  // 2*log2(e)
  return fmaf(-2.0f, __builtin_amdgcn_rcpf(e + 1.0f), 1.0f);
}

__device__ __forceinline__ float sigmoid_(float x) {
  float e = __builtin_amdgcn_exp2f(x * -1.4426950408889634f);
  return __builtin_amdgcn_rcpf(1.0f + e);
}

__device__ __forceinline__ float mlp_f(float y,
    const float (&w1p)[8], float b1v,
    const float (&w2p)[8], float b2v,
    const float (&w3p)[8], float b3v, bool isq1) {
  float G[8];
  gather8(y, G);
  float h1 = fast_tanh(dot8(w1p, G, isq1, b1v));
  gather8(h1, G);
  float h2 = fast_tanh(dot8(w2p, G, isq1, b2v));
  gather8(h2, G);
  return dot8(w3p, G, isq1, b3v);
}

__global__
__attribute__((amdgpu_flat_work_group_size(64, 64), amdgpu_waves_per_eu(1, 1)))
void odern_kernel(
    const float* __restrict__ x_seq,
    const float* __restrict__ w1, const float* __restrict__ b1,
    const float* __restrict__ w2, const float* __restrict__ b2,
    const float* __restrict__ w3, const float* __restrict__ b3,
    const float* __restrict__ gru_wih, const float* __restrict__ gru_whh,
    const float* __restrict__ gru_b, const float* __restrict__ gru_bn,
    const float* __restrict__ pred_w, const float* __restrict__ pred_b,
    float* __restrict__ out) {
  const int tid = threadIdx.x;
  const int j = tid & 15;              // position within row
  const bool isq1 = (tid & 16) != 0;   // K-split group
  const int s = tid >> 5;              // sample-in-wave 0..1
  const int b = blockIdx.x * 2 + s;
  const int R = (tid & 31) >= 16 ? ((j + 8) & 15) : j;  // owned output row

  // per-lane weight slices: wm[c] = M[R][(j+c)&15]
  float w1p[8], w2p[8], w3p[8], whp[8], wzp[8], wnp[8];
#pragma unroll
  for (int c = 0; c < 8; ++c) {
    const int i = (j + c) & 15;
    w1p[c] = w1[R * 16 + i];
    w2p[c] = w2[R * 16 + i];
    w3p[c] = w3[R * 16 + i];
    whp[c] = gru_whh[R * 16 + i];
    wzp[c] = gru_whh[(16 + R) * 16 + i];
    wnp[c] = gru_whh[(32 + R) * 16 + i];
  }
  // per-element constants use plain index j (dot results are normalized)
  const float b1v = b1[j], b2v = b2[j], b3v = b3[j];
  const float wih_r0 = gru_wih[j * 2],        wih_r1 = gru_wih[j * 2 + 1];
  const float wih_z0 = gru_wih[(16 + j) * 2], wih_z1 = gru_wih[(16 + j) * 2 + 1];
  const float wih_n0 = gru_wih[(32 + j) * 2], wih_n1 = gru_wih[(32 + j) * 2 + 1];
  const float gb_r = gru_b[j], gb_z = gru_b[16 + j], gb_n = gru_b[32 + j];
  const float bnv = gru_bn[j];
  const float pwv = pred_w[j], pbv = pred_b[0];

  const float* xp = x_seq + (size_t)b * (T_STEPS * 2);

  float h = 0.0f;
#pragma unroll 1
  for (int t = 0; t < T_STEPS; ++t) {
    const float x0 = xp[2 * t];
    const float x1 = xp[2 * t + 1];

    // ---- adaptive Tsit5 from t=0 to t=1, <=16 iterations, early exit ----
    float y = h;
    float tt = 0.0f, dt = 1.0f;
    float k1 = mlp_f(y, w1p, b1v, w2p, b2v, w3p, b3v, isq1);
#pragma unroll 1
    for (int sidx = 0; sidx < N_ODE_STEPS; ++sidx) {
      // Once tt == 1.0 for both samples in the wave, remaining reference
      // iterations are bitwise no-ops -> skip. Wave-uniform branch.
      if (__all(tt >= 1.0f)) break;

      const float dt_c = fminf(dt, 1.0f - tt);
      const float d = dt_c;

      float s2 = 0.161f * k1;
      float k2 = mlp_f(fmaf(d, s2, y), w1p, b1v, w2p, b2v, w3p, b3v, isq1);

      float s3 = fmaf(0.335480655492357f, k2, -0.008480655492356989f * k1);
      float k3 = mlp_f(fmaf(d, s3, y), w1p, b1v, w2p, b2v, w3p, b3v, isq1);

      float s4 = fmaf(4.3622954328695815f, k3,
                 fmaf(-6.359448489975075f, k2, 2.8971530571054935f * k1));
      float k4 = mlp_f(fmaf(d, s4, y), w1p, b1v, w2p, b2v, w3p, b3v, isq1);

      float s5 = fmaf(-0.09249506636175525f, k4,
                 fmaf(7.4955393428898365f, k3,
                 fmaf(-11.748883564062828f, k2, 5.325864828439257f * k1)));
      float k5 = mlp_f(fmaf(d, s5, y), w1p, b1v, w2p, b2v, w3p, b3v, isq1);

      float s6 = fmaf(-0.028269050394068383f, k5,
                 fmaf(-0.071584973281401f, k4,
                 fmaf(8.159367898576159f, k3,
                 fmaf(-12.92096931784711f, k2, 5.86145544294642f * k1))));
      float k6 = mlp_f(fmaf(d, s6, y), w1p, b1v, w2p, b2v, w3p, b3v, isq1);

      float sy = fmaf(2.324710524099774f, k6,
                 fmaf(-3.290069515436081f, k5,
                 fmaf(1.379008574103742f, k4,
                 fmaf(0.4798896504144996f, k3,
                 fmaf(0.01f, k2, 0.09646076681806523f * k1)))));
      float y_new = fmaf(d, sy, y);

      float k7 = mlp_f(y_new, w1p, b1v, w2p, b2v, w3p, b3v, isq1);

      float se = fmaf(0.015151515151515152f, k7,
                 fmaf(-0.45808210592918697f, k6,
                 fmaf(0.5823571654525552f, k5,
                 fmaf(-0.1447110071732629f, k4,
                 fmaf(0.007880878010261995f, k3,
                 fmaf(-0.0008164344596567469f, k2, -0.001780011052225777f * k1))))));
      float err = d * se;

      float scale = fmaf(0.01f, fmaxf(fabsf(y), fabsf(y_new)), 0.0001f);
      float r = err * __builtin_amdgcn_rcpf(scale);
      float m = rsum16(r * r) * 0.0625f;   // mean over the 16 hidden dims
      float err2 = fmaxf(m, 1e-16f);

      const bool acc = err2 <= 1.0f;
      y = acc ? y_new : y;
      tt = acc ? tt + dt_c : tt;
      k1 = acc ? k7 : k1;   // FSAL: f(y_new) == k7 bitwise, else keep k1

      float fac = 0.9f * __builtin_amdgcn_exp2f(-0.1f * __builtin_amdgcn_logf(err2));
      fac = fminf(fmaxf(fac, 0.2f), 10.0f);
      dt = dt_c * fac;
    }

    // ---- GRU update: one shared gather feeds all 3 dots ----
    float ir = fmaf(wih_r1, x1, fmaf(wih_r0, x0, gb_r));
    float iz = fmaf(wih_z1, x1, fmaf(wih_z0, x0, gb_z));
    float in_ = fmaf(wih_n1, x1, fmaf(wih_n0, x0, gb_n));
    float G[8];
    gather8(y, G);
    float pre_r = dot8(whp, G, isq1, ir);    // ir + hr
    float pre_z = dot8(wzp, G, isq1, iz);    // iz + hz
    float hnb   = dot8(wnp, G, isq1, bnv);   // hn + bn
    float rg = sigmoid_(pre_r);
    float zg = sigmoid_(pre_z);
    float ng = fast_tanh(fmaf(rg, hnb, in_));
    h = fmaf(zg, y - ng, ng);
  }

  // ---- final projection: out[b] = h . pred_w + pred_b ----
  float ps = rsum16(h * pwv);
  if ((tid & 31) == 0) out[b] = ps + pbv;
}

extern "C" void kernel_launch(void* const* d_in, const int* in_sizes, int n_in,
                              void* d_out, int out_size, void* d_ws, size_t ws_size,
                              hipStream_t stream) {
  (void)in_sizes; (void)n_in; (void)out_size; (void)d_ws; (void)ws_size;
  odern_kernel<<<dim3(NB / 2), dim3(64), 0, stream>>>(
      (const float*)d_in[0],
      (const float*)d_in[1], (const float*)d_in[2],
      (const float*)d_in[3], (const float*)d_in[4],
      (const float*)d_in[5], (const float*)d_in[6],
      (const float*)d_in[7], (const float*)d_in[8],
      (const float*)d_in[9], (const float*)d_in[10],
      (const float*)d_in[11], (const float*)d_in[12],
      (float*)d_out);
}